// Round 12
// baseline (30.859 us; speedup 1.0000x reference)
//
#include <hip/hip_runtime.h>
#include <stdint.h>

// Problem constants
#define NBATCH 1024
#define NQ 300
#define NC 80
#define QC 24000       // NQ * NC floats per batch
#define NF4 6000       // QC / 4
#define TOPK 300
#define RSEL 384u      // fast-path lower guard / radix select rank
#define NSLICE 4       // K1 slices per batch
#define SELEM 6000     // elements per slice
#define SF4 1500       // float4 per slice
#define NT1 256        // K1 threads
#define SEGCAP 768     // per-slice candidate segment capacity
#define NT 256         // K2 threads (pick/scan parameterized on this)
#define LG (NT / 64)   // part entries per wave0 lane (=4)
#define RG (2048 / NT) // rank-hist buckets per thread (=8)
#define NB1 2048       // radix coarse buckets (key bits [31:21])
#define SH1 21
#define SH2 13
#define SELCAP 2048
#define FINCAP 768
#define THRESH 2.0f    // prefilter: candidate iff logit >= 2.0 (E[cnt]~546/batch)
#define NBH 2048       // rank histogram buckets
#define SBASE 0x3F600000u   // 0.875f; fast-path scores >= sigmoid(2.0)=0.8808

// order-preserving f32-bits -> u32 key (branchless)
__device__ __forceinline__ uint32_t xform(uint32_t u) {
    return u ^ (uint32_t)(((int32_t)u >> 31) | 0x80000000);
}

__device__ __forceinline__ uint32_t sbucket(uint32_t sbits) {
    int32_t d = (int32_t)(sbits - SBASE);
    d = d < 0 ? 0 : d;
    uint32_t bkt = ((uint32_t)d) >> 10;
    return bkt > (NBH - 1) ? (NBH - 1) : bkt;
}

// ===========================================================================
// K1: stream + prefilter + segment compact. No global atomics.
// ===========================================================================
__global__ void __launch_bounds__(NT1, 8)
k1_stream(const float* __restrict__ logits, uint32_t* __restrict__ cnts,
          uint64_t* __restrict__ buf) {
    __shared__ uint32_t scnt;
    __shared__ uint64_t sbuf[SEGCAP];
    const int tid = threadIdx.x;
    const int blk = blockIdx.x;            // = b*NSLICE + sl
    const int b   = blk >> 2;
    const int sl  = blk & 3;
    const float4* lg4 = reinterpret_cast<const float4*>(logits + (size_t)b * QC) + sl * SF4;

    if (tid == 0) scnt = 0;
    __syncthreads();

#pragma unroll
    for (int k = 0; k < 6; ++k) {
        const int i4 = tid + (k << 8);
        if (k < 5 || i4 < SF4) {           // 1500 = 5*256 + 220
            float4 v = lg4[i4];
            float f[4] = { v.x, v.y, v.z, v.w };
#pragma unroll
            for (int c = 0; c < 4; ++c) {
                if (f[c] >= THRESH) {
                    uint32_t key = xform(__float_as_uint(f[c]));
                    uint32_t idx = (uint32_t)(sl * SELEM) + 4u * (uint32_t)i4 + (uint32_t)c;
                    uint32_t pos = atomicAdd(&scnt, 1u);   // LDS atomic, ~137 hits/block
                    if (pos < SEGCAP)
                        sbuf[pos] = ((uint64_t)key << 32) | (uint64_t)(0xFFFFFFFFu - idx);
                }
            }
        }
    }
    __syncthreads();
    const uint32_t n = scnt;
    if (tid == 0) cnts[blk] = n;           // true count (truncation detectable)
    const uint32_t m = n > SEGCAP ? SEGCAP : n;
    for (uint32_t i = tid; i < m; i += NT1)
        buf[(size_t)blk * SEGCAP + i] = sbuf[i];
}

// ---------------------------------------------------------------------------
// pick<NB,ZERO>: hist[NB] finalized -> bucket (from top) containing the rem-th
// largest + residual inside it. ZERO re-zeroes hist. NT=256 parameterization.
// ---------------------------------------------------------------------------
template<int NB, bool ZERO>
__device__ __forceinline__ void pick(uint32_t* __restrict__ hist,
                                     uint32_t* __restrict__ part,
                                     uint32_t* __restrict__ gsufx,
                                     uint32_t* __restrict__ misc,
                                     int tid, uint32_t rem,
                                     uint32_t* bucket_out, uint32_t* rem_out) {
    constexpr int G = (NB >= NT) ? (NB / NT) : 1;
    const int base = tid * G;
    uint32_t h[G];
    uint32_t s = 0;
    if (base < NB) {
#pragma unroll
        for (int u = 0; u < G; ++u) { h[u] = hist[base + u]; s += h[u]; }
        if (ZERO) {
#pragma unroll
            for (int u = 0; u < G; ++u) hist[base + u] = 0;
        }
    } else {
#pragma unroll
        for (int u = 0; u < G; ++u) h[u] = 0;
    }
    part[tid] = s;
    __syncthreads();

    if (tid < 64) {
        uint32_t gs = 0;
#pragma unroll
        for (int u = 0; u < LG; ++u) gs += part[tid * LG + u];
        uint32_t S = gs;
#pragma unroll
        for (int off = 1; off < 64; off <<= 1) {
            uint32_t v = __shfl_down(S, off, 64);
            if (tid + off < 64) S += v;
        }
        gsufx[tid] = S;
        if (tid == 0) gsufx[64] = 0;
    }
    __syncthreads();

    const int g = tid / LG;
    uint32_t A = gsufx[g + 1];
    for (int t2 = tid + 1; t2 < (g + 1) * LG; ++t2) A += part[t2];
    if (base < NB && A < rem && A + s >= rem) {
        uint32_t acc = 0, bsel = (uint32_t)base, r = 1;
#pragma unroll
        for (int u = G - 1; u >= 0; --u) {
            if (A + acc + h[u] >= rem) { bsel = (uint32_t)(base + u); r = rem - A - acc; break; }
            acc += h[u];
        }
        misc[0] = bsel;
        misc[1] = r;
    }
    __syncthreads();
    *bucket_out = misc[0];
    *rem_out    = misc[1];
}

// ===========================================================================
// K2: per-batch select + exact rank + output.
// ===========================================================================
__global__ void __launch_bounds__(NT, 4)
k2_select(const float* __restrict__ logits, const float* __restrict__ pboxes,
          const float* __restrict__ sizes, const uint32_t* __restrict__ cnts,
          const uint64_t* __restrict__ buf, float* __restrict__ out) {
    __shared__ __align__(16) uint32_t hist[NBH + 1];  // sentinel stays 0
    __shared__ uint64_t cand[SELCAP];                 // 16KB
    __shared__ uint64_t srt[FINCAP];                  // 6KB
    __shared__ uint32_t part[NT];
    __shared__ uint32_t gsufx[65];
    __shared__ uint32_t misc[4];
    __shared__ uint32_t soff[NSLICE];                 // segment load offsets
    __shared__ uint32_t sinfo[2];                     // [0]=total true cnt, [1]=truncated flag

    const int tid = threadIdx.x;
    const int b   = blockIdx.x;
    const float4* lg4 = reinterpret_cast<const float4*>(logits + (size_t)b * QC);

    for (int i = tid; i <= NBH; i += NT) hist[i] = 0;
    if (tid == 0) {
        uint32_t tot = 0, trunc = 0;
        for (int s = 0; s < NSLICE; ++s) {
            uint32_t c = cnts[b * NSLICE + s];
            soff[s] = tot;                 // offset assuming no truncation
            tot += c;
            if (c > SEGCAP) trunc = 1;
        }
        sinfo[0] = tot; sinfo[1] = trunc;
        misc[2] = 0; misc[3] = 0;
    }
    __syncthreads();

    const uint32_t cnt   = sinfo[0];
    const uint32_t trunc = sinfo[1];
    const bool ldsResident = (!trunc && cnt <= SELCAP && cnt >= RSEL);

    // ---- load segments into LDS (valid whenever no truncation & fits) ----
    if (!trunc && cnt <= SELCAP) {
#pragma unroll
        for (int s = 0; s < NSLICE; ++s) {
            uint32_t c = cnts[b * NSLICE + s];   // == stored amount (no trunc)
            uint32_t o = soff[s];
            const uint64_t* src = buf + (size_t)(b * NSLICE + s) * SEGCAP;
            for (uint32_t i = tid; i < c; i += NT) cand[o + i] = src[i];
        }
    }
    __syncthreads();

    uint32_t n2;

    if (ldsResident && cnt <= FINCAP) {
        // ==== FAST PATH: all candidates finalists; sigmoid + rank-hist fused ====
        for (uint32_t i = tid; i < cnt; i += NT) {
            uint64_t e = cand[i];
            uint32_t k = (uint32_t)(e >> 32);
            uint32_t bits = (k & 0x80000000u) ? (k & 0x7FFFFFFFu) : ~k;
            float x  = __uint_as_float(bits);
            float sc = 1.0f / (1.0f + expf(-x));
            uint32_t sb = __float_as_uint(sc);
            srt[i] = ((uint64_t)sb << 32) | (uint64_t)(uint32_t)e;
            atomicAdd(&hist[sbucket(sb)], 1u);
        }
        n2 = cnt;
    } else if (ldsResident) {
        // ==== LDS RADIX over candidates (768 < cnt <= 2048) ====
        for (uint32_t i = tid; i < cnt; i += NT)
            atomicAdd(&hist[(uint32_t)(cand[i] >> 32) >> SH1], 1u);
        __syncthreads();
        uint32_t b1, r1;
        pick<NB1, true>(hist, part, gsufx, misc, tid, RSEL, &b1, &r1);  // re-zeroes hist
        for (uint32_t i = tid; i < cnt; i += NT) {
            uint32_t k = (uint32_t)(cand[i] >> 32);
            if ((k >> SH1) == b1) atomicAdd(&hist[(k >> SH2) & 0xFFu], 1u);
        }
        __syncthreads();
        uint32_t t2, r2;
        pick<256, false>(hist, part, gsufx, misc, tid, r1, &t2, &r2);
        (void)r2;
        const uint32_t T2 = (b1 << SH1) | (t2 << SH2);
        for (uint32_t i = tid; i < cnt; i += NT) {
            uint64_t e = cand[i];
            uint32_t k = (uint32_t)(e >> 32);
            if (k >= T2) {
                uint32_t bits = (k & 0x80000000u) ? (k & 0x7FFFFFFFu) : ~k;
                float x  = __uint_as_float(bits);
                float sc = 1.0f / (1.0f + expf(-x));
                uint32_t pos = atomicAdd(&misc[3], 1u);
                if (pos < FINCAP)
                    srt[pos] = ((uint64_t)__float_as_uint(sc) << 32) | (uint64_t)(uint32_t)e;
            }
        }
        __syncthreads();
        uint32_t m3 = misc[3];
        n2 = m3 > FINCAP ? FINCAP : m3;
        for (int i = tid; i < 256; i += NT) hist[i] = 0;   // dirtied refine region
        // rank-hist over finalists
        __syncthreads();
        for (uint32_t i = tid; i < n2; i += NT)
            atomicAdd(&hist[sbucket((uint32_t)(srt[i] >> 32))], 1u);
    } else {
        // ==== FULL FALLBACK: re-read logits, global radix (exact; ~never) ====
        for (int i4 = tid; i4 < NF4; i4 += NT) {
            float4 v = lg4[i4];
            atomicAdd(&hist[xform(__float_as_uint(v.x)) >> SH1], 1u);
            atomicAdd(&hist[xform(__float_as_uint(v.y)) >> SH1], 1u);
            atomicAdd(&hist[xform(__float_as_uint(v.z)) >> SH1], 1u);
            atomicAdd(&hist[xform(__float_as_uint(v.w)) >> SH1], 1u);
        }
        __syncthreads();
        uint32_t b1, r1;
        pick<NB1, true>(hist, part, gsufx, misc, tid, RSEL, &b1, &r1);
        for (int i4 = tid; i4 < NF4; i4 += NT) {
            float4 v = lg4[i4];
            uint32_t kk[4] = { xform(__float_as_uint(v.x)), xform(__float_as_uint(v.y)),
                               xform(__float_as_uint(v.z)), xform(__float_as_uint(v.w)) };
#pragma unroll
            for (int c = 0; c < 4; ++c) {
                uint32_t k = kk[c];
                uint32_t bk = k >> SH1;
                if (bk >= b1) {
                    uint32_t pos = atomicAdd(&misc[2], 1u);
                    uint32_t idx = 4u * (uint32_t)i4 + (uint32_t)c;
                    if (pos < SELCAP)
                        cand[pos] = ((uint64_t)k << 32) | (uint64_t)(0xFFFFFFFFu - idx);
                    if (bk == b1) atomicAdd(&hist[(k >> SH2) & 0xFFu], 1u);
                }
            }
        }
        __syncthreads();
        uint32_t t2, r2;
        pick<256, false>(hist, part, gsufx, misc, tid, r1, &t2, &r2);
        (void)r2;
        const uint32_t T2 = (b1 << SH1) | (t2 << SH2);
        uint32_t c2 = misc[2];
        uint32_t nn = c2 > SELCAP ? SELCAP : c2;
        for (uint32_t i = tid; i < nn; i += NT) {
            uint64_t e = cand[i];
            uint32_t k = (uint32_t)(e >> 32);
            if (k >= T2) {
                uint32_t bits = (k & 0x80000000u) ? (k & 0x7FFFFFFFu) : ~k;
                float x  = __uint_as_float(bits);
                float sc = 1.0f / (1.0f + expf(-x));
                uint32_t pos = atomicAdd(&misc[3], 1u);
                if (pos < FINCAP)
                    srt[pos] = ((uint64_t)__float_as_uint(sc) << 32) | (uint64_t)(uint32_t)e;
            }
        }
        __syncthreads();
        uint32_t m3 = misc[3];
        n2 = m3 > FINCAP ? FINCAP : m3;
        for (int i = tid; i < 256; i += NT) hist[i] = 0;
        __syncthreads();
        for (uint32_t i = tid; i < n2; i += NT)
            atomicAdd(&hist[sbucket((uint32_t)(srt[i] >> 32))], 1u);
    }
    __syncthreads();

    // ==== counting rank over srt[0..n2) ====
    // suffix scan: hist[b] <- G[b]
    {
        const int base = tid * RG;
        uint32_t h[RG];
        uint32_t s = 0;
#pragma unroll
        for (int u = 0; u < RG; ++u) { h[u] = hist[base + u]; s += h[u]; }
        part[tid] = s;
        __syncthreads();
        if (tid < 64) {
            uint32_t gs = 0;
#pragma unroll
            for (int u = 0; u < LG; ++u) gs += part[tid * LG + u];
            uint32_t S = gs;
#pragma unroll
            for (int off = 1; off < 64; off <<= 1) {
                uint32_t v = __shfl_down(S, off, 64);
                if (tid + off < 64) S += v;
            }
            gsufx[tid] = S;
            if (tid == 0) gsufx[64] = 0;
        }
        __syncthreads();
        const int g = tid / LG;
        uint32_t A = gsufx[g + 1];
        for (int t2 = tid + 1; t2 < (g + 1) * LG; ++t2) A += part[t2];
        uint32_t acc = A;
#pragma unroll
        for (int u = RG - 1; u >= 0; --u) { hist[base + u] = acc; acc += h[u]; }
    }
    __syncthreads();

    // scatter into bucket-sorted order (cand reused as dst; never aliases srt)
    for (uint32_t i = tid; i < n2; i += NT) {
        uint64_t k = srt[i];
        uint32_t slot = atomicAdd(&hist[sbucket((uint32_t)(k >> 32))], 1u);
        cand[slot] = k;
    }
    __syncthreads();

    // exact rank = G[b] + same-bucket peers with greater key; fused epilogue
    for (uint32_t i = tid; i < n2; i += NT) {
        uint64_t my = srt[i];
        uint32_t bkt = sbucket((uint32_t)(my >> 32));
        uint32_t seg0 = hist[bkt + 1];
        uint32_t seg1 = hist[bkt];
        uint32_t rank = seg0;
        for (uint32_t j = seg0; j < seg1; ++j)
            rank += (cand[j] > my) ? 1u : 0u;
        if (rank < TOPK) {
            uint32_t idx = 0xFFFFFFFFu - (uint32_t)(my & 0xFFFFFFFFull);
            uint32_t lab = idx % NC;
            uint32_t q   = idx / NC;
            float4 bx = reinterpret_cast<const float4*>(pboxes)[(size_t)b * NQ + q];
            float sw = sizes[2 * b + 0];
            float sh = sizes[2 * b + 1];
            float hw = 0.5f * bx.z, hh = 0.5f * bx.w;
            float4 o;
            o.x = (bx.x - hw) * sw;
            o.y = (bx.y - hh) * sh;
            o.z = (bx.x + hw) * sw;
            o.w = (bx.y + hh) * sh;
            out[(size_t)b * TOPK + rank] = (float)lab;                                    // labels
            reinterpret_cast<float4*>(out + (size_t)NBATCH * TOPK)[(size_t)b * TOPK + rank] = o; // boxes
            out[(size_t)NBATCH * TOPK * 5 + (size_t)b * TOPK + rank] =
                __uint_as_float((uint32_t)(my >> 32));                                    // scores
        }
    }
}

extern "C" void kernel_launch(void* const* d_in, const int* in_sizes, int n_in,
                              void* d_out, int out_size, void* d_ws, size_t ws_size,
                              hipStream_t stream) {
    const float* logits = (const float*)d_in[0];   // [1024,300,80] f32
    const float* pboxes = (const float*)d_in[1];   // [1024,300,4]  f32
    const float* sizes  = (const float*)d_in[2];   // [1024,2]      f32
    float* out = (float*)d_out;                    // labels | boxes | scores (flat f32)

    uint32_t* cnts = (uint32_t*)d_ws;                                   // 4096 u32
    uint64_t* buf  = (uint64_t*)((char*)d_ws + 16384);                  // 4096*768 u64 (~25MB)

    hipLaunchKernelGGL(k1_stream, dim3(NBATCH * NSLICE), dim3(NT1), 0, stream,
                       logits, cnts, buf);
    hipLaunchKernelGGL(k2_select, dim3(NBATCH), dim3(NT), 0, stream,
                       logits, pboxes, sizes, cnts, buf, out);
}